// Round 1
// baseline (2847.610 us; speedup 1.0000x reference)
//
#include <hip/hip_runtime.h>

// Problem constants (fixed by the reference file)
constexpr int D_IN  = 128;
constexpr int D_OUT = 64;
constexpr int NCH   = 2;
constexpr int NUM_A = 4;
constexpr int COLS  = NCH * D_OUT;   // 128 (channel-interleaved Hc width)

// ---------------------------------------------------------------------------
// Kernel 1: score[c][a] = 0.5 * softmax_a( mean_d att[c][d][a] )
// One wave; lanes 0..7 each own one (c,a).
// ---------------------------------------------------------------------------
__global__ __launch_bounds__(64) void score_kernel(const float* __restrict__ att,
                                                   float* __restrict__ score) {
    int lane = threadIdx.x;
    int c = lane >> 2, a = lane & 3;
    float s = 0.0f;
    if (lane < 8) {
        const float* p = att + c * (D_IN * NUM_A) + a;
        for (int d = 0; d < D_IN; ++d) s += p[d * NUM_A];
        s *= (1.0f / D_IN);
    }
    // softmax over groups of 4 lanes (same c): butterfly within xor-1,2
    float m = fmaxf(s, __shfl_xor(s, 1));
    m = fmaxf(m, __shfl_xor(m, 2));
    float ex = __expf(s - m);
    float sum = ex + __shfl_xor(ex, 1);
    sum += __shfl_xor(sum, 2);
    if (lane < 8) score[lane] = 0.5f * ex / sum;   // fold the channel-mean 0.5 in
}

// ---------------------------------------------------------------------------
// Kernel 2: Hc[n][c*64+o] = sum_k H[n][k] * W[c][k][o]
// Block: 256 threads = 64 col-pairs x 4 row-groups; 32 rows per block.
// H tile staged in LDS; W read through cache (64 KB, L1/L2 resident).
// ---------------------------------------------------------------------------
__global__ __launch_bounds__(256) void gemm_kernel(const float* __restrict__ H,
                                                   const float* __restrict__ W,
                                                   float* __restrict__ Hc, int N) {
    __shared__ float Hs[32 * D_IN];          // 16 KB
    const int t    = threadIdx.x;
    const int row0 = blockIdx.x * 32;
    const int nvalid = min(32, N - row0);

    // stage H tile (nvalid rows x 128 f32) via float4
    const float4* src = reinterpret_cast<const float4*>(H + (size_t)row0 * D_IN);
    float4* dst = reinterpret_cast<float4*>(Hs);
    const int nf4 = nvalid * (D_IN / 4);     // up to 1024
    for (int i = t; i < nf4; i += 256) dst[i] = src[i];
    __syncthreads();

    const int pair = t & 63;                 // 0..63 -> cols 2p, 2p+1
    const int rg   = t >> 6;                 // 0..3  -> rows rg*8 .. rg*8+7
    const int co0  = pair * 2;
    const int c    = co0 >> 6;
    const int o    = co0 & 63;

    const float* Wp = W + c * (D_IN * D_OUT) + o;   // stride D_OUT per k
    const float* hs = Hs + rg * 8 * D_IN;

    float acc[8][2];
    #pragma unroll
    for (int r = 0; r < 8; ++r) { acc[r][0] = 0.f; acc[r][1] = 0.f; }

    #pragma unroll 4
    for (int k = 0; k < D_IN; ++k) {
        const float2 w = *reinterpret_cast<const float2*>(Wp + k * D_OUT);
        #pragma unroll
        for (int r = 0; r < 8; ++r) {
            const float h = hs[r * D_IN + k];
            acc[r][0] += h * w.x;
            acc[r][1] += h * w.y;
        }
    }

    #pragma unroll
    for (int r = 0; r < 8; ++r) {
        const int row = row0 + rg * 8 + r;
        if (row < N) {
            float2 v = make_float2(acc[r][0], acc[r][1]);
            *reinterpret_cast<float2*>(Hc + (size_t)row * COLS + co0) = v;
        }
    }
}

// ---------------------------------------------------------------------------
// Kernel 3: edge-parallel SpMM, both channels fused.
// 16 lanes per edge; each lane handles 4 output dims (float4) per channel.
// out[row][d] += score0[a]*val*Hc0[col][d] + score1[a]*val*Hc1[col][d]
// ---------------------------------------------------------------------------
__global__ __launch_bounds__(256) void spmm_kernel(const int* __restrict__ rows,
                                                   const int* __restrict__ cols,
                                                   const float* __restrict__ vals,
                                                   const float* __restrict__ Hc,
                                                   const float* __restrict__ score,
                                                   float* __restrict__ out,
                                                   int TE, int Eper) {
    const int g   = blockIdx.x * 256 + threadIdx.x;
    const int e   = g >> 4;
    const int sub = g & 15;
    if (e >= TE) return;

    const int   row = rows[e];
    const int   col = cols[e];
    const float val = vals[e];
    const int   a   = (int)((unsigned)e / (unsigned)Eper);

    const float w0 = score[a]     * val;
    const float w1 = score[4 + a] * val;

    const float4* h = reinterpret_cast<const float4*>(Hc + (size_t)col * COLS);
    const float4 h0 = h[sub];        // channel 0, dims sub*4..sub*4+3
    const float4 h1 = h[16 + sub];   // channel 1

    float4 msg;
    msg.x = w0 * h0.x + w1 * h1.x;
    msg.y = w0 * h0.y + w1 * h1.y;
    msg.z = w0 * h0.z + w1 * h1.z;
    msg.w = w0 * h0.w + w1 * h1.w;

    float* op = out + (size_t)row * D_OUT + sub * 4;
    atomicAdd(op + 0, msg.x);
    atomicAdd(op + 1, msg.y);
    atomicAdd(op + 2, msg.z);
    atomicAdd(op + 3, msg.w);
}

// ---------------------------------------------------------------------------
extern "C" void kernel_launch(void* const* d_in, const int* in_sizes, int n_in,
                              void* d_out, int out_size, void* d_ws, size_t ws_size,
                              hipStream_t stream) {
    const float* H    = (const float*)d_in[0];  // [N,128]
    const float* vals = (const float*)d_in[1];  // [4,E]
    const float* W    = (const float*)d_in[2];  // [2,128,64]
    const float* att  = (const float*)d_in[3];  // [2,128,4]
    const int*   rows = (const int*)d_in[4];    // [4,E]
    const int*   cols = (const int*)d_in[5];    // [4,E]

    const int N    = in_sizes[0] / D_IN;        // 50000
    const int TE   = in_sizes[1];               // 3.2M
    const int Eper = TE / NUM_A;                // 800000

    float* ws_score = (float*)d_ws;                              // 8 floats
    float* ws_Hc    = (float*)((char*)d_ws + 256);               // [N][128] f32

    // out is poisoned before every timed launch -> zero it (atomic accumulate target)
    hipMemsetAsync(d_out, 0, (size_t)out_size * sizeof(float), stream);

    score_kernel<<<1, 64, 0, stream>>>(att, ws_score);

    const int gemm_blocks = (N + 31) / 32;
    gemm_kernel<<<gemm_blocks, 256, 0, stream>>>(H, W, ws_Hc, N);

    const long long spmm_threads = (long long)TE * 16;
    const int spmm_blocks = (int)((spmm_threads + 255) / 256);
    spmm_kernel<<<spmm_blocks, 256, 0, stream>>>(rows, cols, vals, ws_Hc, ws_score,
                                                 (float*)d_out, TE, Eper);
}

// Round 2
// 829.693 us; speedup vs baseline: 3.4321x; 3.4321x over previous
//
#include <hip/hip_runtime.h>

// Problem constants (fixed by the reference file)
constexpr int D_IN  = 128;
constexpr int D_OUT = 64;
constexpr int NCH   = 2;
constexpr int NUM_A = 4;
constexpr int COLS  = NCH * D_OUT;   // 128 (channel-interleaved Hc width)

// ---------------------------------------------------------------------------
// Kernel 1: score[c][a] = 0.5 * softmax_a( mean_d att[c][d][a] )
// ---------------------------------------------------------------------------
__global__ __launch_bounds__(64) void score_kernel(const float* __restrict__ att,
                                                   float* __restrict__ score) {
    int lane = threadIdx.x;
    int c = lane >> 2, a = lane & 3;
    float s = 0.0f;
    if (lane < 8) {
        const float* p = att + c * (D_IN * NUM_A) + a;
        for (int d = 0; d < D_IN; ++d) s += p[d * NUM_A];
        s *= (1.0f / D_IN);
    }
    float m = fmaxf(s, __shfl_xor(s, 1));
    m = fmaxf(m, __shfl_xor(m, 2));
    float ex = __expf(s - m);
    float sum = ex + __shfl_xor(ex, 1);
    sum += __shfl_xor(sum, 2);
    if (lane < 8) score[lane] = 0.5f * ex / sum;   // fold the channel-mean 0.5 in
}

// ---------------------------------------------------------------------------
// Kernel 2: Hc[n][c*64+o] = sum_k H[n][k] * W[c][k][o]
// ---------------------------------------------------------------------------
__global__ __launch_bounds__(256) void gemm_kernel(const float* __restrict__ H,
                                                   const float* __restrict__ W,
                                                   float* __restrict__ Hc, int N) {
    __shared__ float Hs[32 * D_IN];          // 16 KB
    const int t    = threadIdx.x;
    const int row0 = blockIdx.x * 32;
    const int nvalid = min(32, N - row0);

    const float4* src = reinterpret_cast<const float4*>(H + (size_t)row0 * D_IN);
    float4* dst = reinterpret_cast<float4*>(Hs);
    const int nf4 = nvalid * (D_IN / 4);
    for (int i = t; i < nf4; i += 256) dst[i] = src[i];
    __syncthreads();

    const int pair = t & 63;
    const int rg   = t >> 6;
    const int co0  = pair * 2;
    const int c    = co0 >> 6;
    const int o    = co0 & 63;

    const float* Wp = W + c * (D_IN * D_OUT) + o;
    const float* hs = Hs + rg * 8 * D_IN;

    float acc[8][2];
    #pragma unroll
    for (int r = 0; r < 8; ++r) { acc[r][0] = 0.f; acc[r][1] = 0.f; }

    #pragma unroll 4
    for (int k = 0; k < D_IN; ++k) {
        const float2 w = *reinterpret_cast<const float2*>(Wp + k * D_OUT);
        #pragma unroll
        for (int r = 0; r < 8; ++r) {
            const float h = hs[r * D_IN + k];
            acc[r][0] += h * w.x;
            acc[r][1] += h * w.y;
        }
    }

    #pragma unroll
    for (int r = 0; r < 8; ++r) {
        const int row = row0 + rg * 8 + r;
        if (row < N) {
            float2 v = make_float2(acc[r][0], acc[r][1]);
            *reinterpret_cast<float2*>(Hc + (size_t)row * COLS + co0) = v;
        }
    }
}

// ---------------------------------------------------------------------------
// Kernel 3: histogram of destination rows
// ---------------------------------------------------------------------------
__global__ __launch_bounds__(256) void hist_kernel(const int* __restrict__ rows,
                                                   unsigned* __restrict__ counts, int TE) {
    int e = blockIdx.x * 256 + threadIdx.x;
    if (e < TE) atomicAdd(&counts[rows[e]], 1u);
}

// ---------------------------------------------------------------------------
// Kernel 4: exclusive scan of counts -> offsets (and cursor copy). 1 block.
// ---------------------------------------------------------------------------
__global__ __launch_bounds__(1024) void scan_kernel(const unsigned* __restrict__ counts,
                                                    unsigned* __restrict__ offsets,
                                                    unsigned* __restrict__ cursor, int n) {
    __shared__ unsigned part[1024];
    const int t = threadIdx.x;
    const int chunk = (n + 1023) >> 10;
    const int s = t * chunk;
    const int e = min(s + chunk, n);
    unsigned sum = 0;
    for (int i = s; i < e; ++i) sum += counts[i];
    part[t] = sum;
    __syncthreads();
    for (int d = 1; d < 1024; d <<= 1) {
        unsigned v = (t >= d) ? part[t - d] : 0u;
        __syncthreads();
        part[t] += v;
        __syncthreads();
    }
    unsigned run = (t == 0) ? 0u : part[t - 1];
    for (int i = s; i < e; ++i) {
        const unsigned c = counts[i];
        offsets[i] = run;
        cursor[i]  = run;
        run += c;
    }
}

// ---------------------------------------------------------------------------
// Kernel 5: scatter edges into row-sorted records (col | a<<16, val)
// (col < 50000 fits in 16 bits; a in bits 16..17)
// ---------------------------------------------------------------------------
__global__ __launch_bounds__(256) void scatter_kernel(const int* __restrict__ rows,
                                                      const int* __restrict__ cols,
                                                      const float* __restrict__ vals,
                                                      unsigned* __restrict__ cursor,
                                                      uint2* __restrict__ erec,
                                                      int TE, int Eper) {
    int e = blockIdx.x * 256 + threadIdx.x;
    if (e >= TE) return;
    const int row      = rows[e];
    const unsigned col = (unsigned)cols[e];
    const float val    = vals[e];
    const unsigned a   = (unsigned)(e / Eper);
    const unsigned pos = atomicAdd(&cursor[row], 1u);
    erec[pos] = make_uint2(col | (a << 16), __float_as_uint(val));
}

// ---------------------------------------------------------------------------
// Kernel 6: row-parallel SpMM. One wave per row; lane = output dim.
// No output atomics; writes every row (covers zero-init of d_out).
// ---------------------------------------------------------------------------
__global__ __launch_bounds__(256) void rowspmm_kernel(const uint2* __restrict__ erec,
                                                      const unsigned* __restrict__ offsets,
                                                      const unsigned* __restrict__ counts,
                                                      const float* __restrict__ Hc,
                                                      const float* __restrict__ score,
                                                      float* __restrict__ out, int N) {
    __shared__ float sc[8];
    if (threadIdx.x < 8) sc[threadIdx.x] = score[threadIdx.x];
    __syncthreads();

    const int lane = threadIdx.x & 63;
    const int row  = blockIdx.x * 4 + (threadIdx.x >> 6);
    if (row >= N) return;

    const unsigned start = offsets[row];
    const unsigned cnt   = counts[row];

    float acc = 0.0f;
    for (unsigned i = 0; i < cnt; i += 64) {
        const unsigned rem = cnt - i;
        const unsigned m = rem < 64u ? rem : 64u;
        uint2 rec = make_uint2(0u, 0u);
        if ((unsigned)lane < m) rec = erec[start + i + lane];
        for (unsigned j = 0; j < m; ++j) {
            const unsigned meta = __shfl(rec.x, (int)j);
            const float    val  = __uint_as_float(__shfl(rec.y, (int)j));
            const unsigned col  = meta & 0xffffu;
            const unsigned a    = meta >> 16;
            const float w0 = sc[a]     * val;
            const float w1 = sc[4 + a] * val;
            const float* h = Hc + (size_t)col * COLS;
            acc += w0 * h[lane] + w1 * h[64 + lane];
        }
    }
    out[(size_t)row * D_OUT + lane] = acc;
}

// ---------------------------------------------------------------------------
extern "C" void kernel_launch(void* const* d_in, const int* in_sizes, int n_in,
                              void* d_out, int out_size, void* d_ws, size_t ws_size,
                              hipStream_t stream) {
    const float* H    = (const float*)d_in[0];  // [N,128]
    const float* vals = (const float*)d_in[1];  // [4,E]
    const float* W    = (const float*)d_in[2];  // [2,128,64]
    const float* att  = (const float*)d_in[3];  // [2,128,4]
    const int*   rows = (const int*)d_in[4];    // [4,E]
    const int*   cols = (const int*)d_in[5];    // [4,E]

    const int N    = in_sizes[0] / D_IN;        // 50000
    const int TE   = in_sizes[1];               // 3.2M
    const int Eper = TE / NUM_A;                // 800000

    char* ws = (char*)d_ws;
    size_t off = 0;
    float* ws_score = (float*)(ws + off); off += 256;
    float* ws_Hc    = (float*)(ws + off); off += (size_t)N * COLS * sizeof(float);
    off = (off + 255) & ~(size_t)255;
    unsigned* counts  = (unsigned*)(ws + off); off += (size_t)N * sizeof(unsigned);
    off = (off + 255) & ~(size_t)255;
    unsigned* offsets = (unsigned*)(ws + off); off += (size_t)N * sizeof(unsigned);
    off = (off + 255) & ~(size_t)255;
    unsigned* cursor  = (unsigned*)(ws + off); off += (size_t)N * sizeof(unsigned);
    off = (off + 255) & ~(size_t)255;
    uint2* erec       = (uint2*)(ws + off);    off += (size_t)TE * sizeof(uint2);

    hipMemsetAsync(counts, 0, (size_t)N * sizeof(unsigned), stream);

    score_kernel<<<1, 64, 0, stream>>>(att, ws_score);

    const int gemm_blocks = (N + 31) / 32;
    gemm_kernel<<<gemm_blocks, 256, 0, stream>>>(H, W, ws_Hc, N);

    const int eblocks = (TE + 255) / 256;
    hist_kernel<<<eblocks, 256, 0, stream>>>(rows, counts, TE);
    scan_kernel<<<1, 1024, 0, stream>>>(counts, offsets, cursor, N);
    scatter_kernel<<<eblocks, 256, 0, stream>>>(rows, cols, vals, cursor, erec, TE, Eper);

    const int rblocks = (N + 3) / 4;
    rowspmm_kernel<<<rblocks, 256, 0, stream>>>(erec, offsets, counts, ws_Hc, ws_score,
                                                (float*)d_out, N);
}